// Round 11
// baseline (88.033 us; speedup 1.0000x reference)
//
#include <hip/hip_runtime.h>

// ConvAttention collapse:
//   softmax_j(Aq[i]+Ak[j]+ba) == softmax_j(Ak_linear[j])   (i-terms & biases cancel)
//   out[i] = Wv * (sum_j sm[j] * x[j]) + bv                (identical for all i)
// Pipeline: k_prep -> k_z (per-px-quad 25x128 GEMV, in-wave c-split + shfl reduce)
//           -> k_ak (tap shift-sum) -> k_xbar (in-thread softmax + weighted avg)
//           -> k_mat (128x128 matvec, c-split, 16x broadcast store, XCD-swizzled)

#define HW    9216      // 96*96
#define HDIM  96
#define WDIM  96
#define CDIM  128
#define WP    28        // padded taps per row (16B-aligned rows)
#define WGS   904       // per-channel-group LDS stride (896 + 8 bank stagger)

__device__ __forceinline__ void fma4(float4& a, const float4& x, const float4& s) {
    a.x += x.x * s.x; a.y += x.y * s.y; a.z += x.z * s.z; a.w += x.w * s.w;
}
__device__ __forceinline__ void axpy4(float4& o, float w, const float4& v) {
    o.x += w * v.x; o.y += w * v.y; o.z += w * v.z; o.w += w * v.w;
}

// ---------------- K0: prep — weffp padded (blocks 0..13) + Wv^T (14..77) --
// weffp[c'][tap] = sum_c Wk[c][c'] * Wa[(128+c)][tap], rows padded to 28.
__global__ void k_prep(const float* __restrict__ Wk, const float* __restrict__ Wa,
                       const float* __restrict__ Wv,
                       float* __restrict__ weffp, float* __restrict__ wvt) {
    const int b = blockIdx.x;
    if (b < 14) {
        int idx = b * 256 + threadIdx.x;
        if (idx < 128 * WP) {
            int cp = idx / WP, tap = idx % WP;
            float s = 0.f;
            if (tap < 25)
                for (int c = 0; c < 128; ++c)
                    s += Wk[c * 128 + cp] * Wa[(128 + c) * 25 + tap];
            weffp[idx] = s;
        }
    } else {
        int idx = (b - 14) * 256 + threadIdx.x;        // 0..16383
        wvt[(idx & 127) * 128 + (idx >> 7)] = Wv[idx]; // wvt[c'][c] = Wv[c][c']
    }
}

// ---------------- K1: z[j][t][hw] = sum_c weff[c][t] * x[j][c][hw] ---------
// Thread: 1 float4 px-quad x 32 channels. Wave: 16 quads x 4 c-groups;
// groups reduced via shfl_xor(16,32). One weight LDS read feeds 4 pixels.
__global__ __launch_bounds__(256, 2) void k_z(const float* __restrict__ x,
                                              const float* __restrict__ weffp,
                                              float* __restrict__ z) {
    __shared__ float wsm[4 * WGS];   // [cg][cl*28+t], stride 904 staggers banks
    const int tid = threadIdx.x;
    for (int i = tid; i < 4 * WGS; i += 256) {
        int cg = i / WGS, r = i % WGS;
        wsm[i] = (r < 896) ? weffp[cg * 896 + r] : 0.f;
    }
    __syncthreads();

    const int j    = blockIdx.y;
    const int w    = tid >> 6;          // wave 0..3
    const int lane = tid & 63;
    const int cg   = lane >> 4;         // channel group 0..3 (32 ch each)
    const int lq   = lane & 15;         // pixel quad within wave
    const int px   = blockIdx.x * 256 + w * 64 + lq * 4;

    const float* xb = x + (size_t)(j * CDIM + cg * 32) * HW + px;
    const float* wg = wsm + cg * WGS;

    float4 acc[25];
    #pragma unroll
    for (int t = 0; t < 25; ++t) acc[t] = make_float4(0.f, 0.f, 0.f, 0.f);

    #pragma unroll 2
    for (int c = 0; c < 32; ++c) {
        float4 xv = *(const float4*)(xb + (size_t)c * HW);
        const float* wr = wg + c * WP;
        #pragma unroll
        for (int t = 0; t < 25; ++t) {
            float wv = wr[t];
            acc[t].x = fmaf(wv, xv.x, acc[t].x);
            acc[t].y = fmaf(wv, xv.y, acc[t].y);
            acc[t].z = fmaf(wv, xv.z, acc[t].z);
            acc[t].w = fmaf(wv, xv.w, acc[t].w);
        }
    }
    // reduce the 4 channel groups (lane bits 4 and 5)
    #pragma unroll
    for (int t = 0; t < 25; ++t) {
        acc[t].x += __shfl_xor(acc[t].x, 16, 64);
        acc[t].y += __shfl_xor(acc[t].y, 16, 64);
        acc[t].z += __shfl_xor(acc[t].z, 16, 64);
        acc[t].w += __shfl_xor(acc[t].w, 16, 64);
        acc[t].x += __shfl_xor(acc[t].x, 32, 64);
        acc[t].y += __shfl_xor(acc[t].y, 32, 64);
        acc[t].z += __shfl_xor(acc[t].z, 32, 64);
        acc[t].w += __shfl_xor(acc[t].w, 32, 64);
    }
    if (cg == 0) {
        float* zb = z + (size_t)j * 25 * HW + px;
        #pragma unroll
        for (int t = 0; t < 25; ++t)
            *(float4*)(zb + (size_t)t * HW) = acc[t];
    }
}

// ---------------- K2: ak[j][px] = sum_t z[j][t][px + off(t)] (bounded) -----
__global__ __launch_bounds__(256) void k_ak(const float* __restrict__ z,
                                            float* __restrict__ ak) {
    const int j  = blockIdx.y;
    const int px = blockIdx.x * 256 + threadIdx.x;
    const int h = px / WDIM, w = px % WDIM;
    const float* zb = z + (size_t)j * 25 * HW + px;
    float s = 0.f;
    #pragma unroll
    for (int kh = 0; kh < 5; ++kh) {
        const bool rok = (unsigned)(h + kh - 2) < (unsigned)HDIM;
        #pragma unroll
        for (int kw = 0; kw < 5; ++kw) {
            const bool ok = rok && ((unsigned)(w + kw - 2) < (unsigned)WDIM);
            const int t = kh * 5 + kw;
            s += ok ? zb[t * HW + (kh - 2) * WDIM + (kw - 2)] : 0.f;
        }
    }
    ak[(size_t)j * HW + px] = s;
}

// ---------------- fallback conv path (small-ws; proven round 5) ------------
__global__ __launch_bounds__(192) void k_conv(const float* __restrict__ x,
                                              const float* __restrict__ weffp,
                                              float* __restrict__ part) {
    const int j  = blockIdx.x;
    const int rt = blockIdx.y;
    const int g  = blockIdx.z;
    const int c0 = g * 16;
    __shared__ float tile[36 * 104];
    __shared__ float wsm[16 * WP];
    const int tid = threadIdx.x;
    for (int i = tid; i < 16 * WP; i += 192) wsm[i] = weffp[c0 * WP + i];
    const int cq = tid % 24;
    const int rg = tid / 24;
    const int r0 = rg * 4;
    const int rowbase = rt * 32;

    float4 acc[4];
    acc[0] = acc[1] = acc[2] = acc[3] = make_float4(0.f, 0.f, 0.f, 0.f);

    for (int ch = 0; ch < 16; ++ch) {
        const float* xc = x + (size_t)(j * CDIM + c0 + ch) * HW;
        __syncthreads();
        for (int idx = tid; idx < 36 * 26; idx += 192) {
            int r = idx / 26, q = idx % 26;
            int gr = rowbase - 2 + r;
            int gc = q * 4 - 4;
            float4 v = make_float4(0.f, 0.f, 0.f, 0.f);
            if (gr >= 0 && gr < HDIM && gc >= 0 && gc < WDIM)
                v = *(const float4*)(xc + gr * WDIM + gc);
            *(float4*)(tile + r * 104 + q * 4) = v;
        }
        __syncthreads();
        const float* wc = wsm + ch * WP;
        for (int rr = 0; rr < 8; ++rr) {
            const float* trow = tile + (r0 + rr) * 104 + cq * 4;
            float4 a  = *(const float4*)(trow);
            float4 b  = *(const float4*)(trow + 4);
            float4 c4 = *(const float4*)(trow + 8);
            float win[12] = {a.x, a.y, a.z, a.w, b.x, b.y, b.z, b.w,
                             c4.x, c4.y, c4.z, c4.w};
            #pragma unroll
            for (int orow = 0; orow < 4; ++orow) {
                int kh = rr - orow;
                if (kh < 0 || kh > 4) continue;
                #pragma unroll
                for (int kw = 0; kw < 5; ++kw) {
                    float w = wc[kh * 5 + kw];
                    acc[orow].x += w * win[kw + 2];
                    acc[orow].y += w * win[kw + 3];
                    acc[orow].z += w * win[kw + 4];
                    acc[orow].w += w * win[kw + 5];
                }
            }
        }
    }
    float* pr = part + (size_t)(g * 16 + j) * HW;
    #pragma unroll
    for (int orow = 0; orow < 4; ++orow) {
        int row = rowbase + r0 + orow;
        *(float4*)(pr + row * WDIM + cq * 4) = acc[orow];
    }
}

__global__ void k_combine(const float* __restrict__ part, float* __restrict__ ak) {
    const int j  = blockIdx.y;
    const int px = blockIdx.x * 256 + threadIdx.x;
    float s = 0.f;
    #pragma unroll
    for (int g = 0; g < 8; ++g) s += part[(size_t)(g * 16 + j) * HW + px];
    ak[(size_t)j * HW + px] = s;
}

// ---------------- K3: xbar[cp][px] = sum_j softmax_j(ak)[px] * x[j][cp][px] -
__global__ __launch_bounds__(256) void k_xbar(const float* __restrict__ x,
                                              const float* __restrict__ ak,
                                              float* __restrict__ xbar) {
    const int b  = blockIdx.x;
    const int cp = b / 9;
    const int px = (b % 9) * 1024 + threadIdx.x * 4;

    float4 av[16];
    #pragma unroll
    for (int j = 0; j < 16; ++j)
        av[j] = *(const float4*)(ak + (size_t)j * HW + px);

    float4 m = av[0];
    #pragma unroll
    for (int j = 1; j < 16; ++j) {
        m.x = fmaxf(m.x, av[j].x); m.y = fmaxf(m.y, av[j].y);
        m.z = fmaxf(m.z, av[j].z); m.w = fmaxf(m.w, av[j].w);
    }
    float4 tot = make_float4(0.f, 0.f, 0.f, 0.f);
    #pragma unroll
    for (int j = 0; j < 16; ++j) {
        av[j].x = __expf(av[j].x - m.x); av[j].y = __expf(av[j].y - m.y);
        av[j].z = __expf(av[j].z - m.z); av[j].w = __expf(av[j].w - m.w);
        tot.x += av[j].x; tot.y += av[j].y; tot.z += av[j].z; tot.w += av[j].w;
    }
    float4 inv = make_float4(1.f / tot.x, 1.f / tot.y, 1.f / tot.z, 1.f / tot.w);

    float4 acc = make_float4(0.f, 0.f, 0.f, 0.f);
    #pragma unroll
    for (int j = 0; j < 16; ++j) {
        float4 xv = *(const float4*)(x + (size_t)(j * CDIM + cp) * HW + px);
        fma4(acc, xv, av[j]);
    }
    acc.x *= inv.x; acc.y *= inv.y; acc.z *= inv.z; acc.w *= inv.w;
    *(float4*)(xbar + (size_t)cp * HW + px) = acc;
}

// ---------------- K4: out[i][c][px] = Wv*xbar + bv, 16x broadcast ----------
// grid (576, 2): c-split 2-way for occupancy; XCD-chunk px swizzle.
__global__ __launch_bounds__(256) void k_mat(const float* __restrict__ xbar,
                                             const float* __restrict__ wvt,
                                             const float* __restrict__ bv,
                                             float* __restrict__ out) {
    __shared__ float lx[128 * 16];
    const int b    = blockIdx.x;
    const int half = blockIdx.y;
    const int tile = (b & 7) * 72 + (b >> 3);   // 576 = 8 * 72
    const int px0  = tile * 16;
    const int tid  = threadIdx.x;

    #pragma unroll
    for (int i = 0; i < 2; ++i) {
        int lin = tid + i * 256;                // 0..511
        int cp = lin >> 2, q = lin & 3;
        *(float4*)(lx + cp * 16 + q * 4) =
            *(const float4*)(xbar + (size_t)cp * HW + px0 + q * 4);
    }
    __syncthreads();

    const int q = tid & 3;                      // px quad
    const int c = half * 64 + (tid >> 2);       // output channel
    float4 o = make_float4(0.f, 0.f, 0.f, 0.f);
    #pragma unroll 4
    for (int cp = 0; cp < 128; ++cp) {
        float4 xv = *(const float4*)(lx + cp * 16 + q * 4);
        axpy4(o, wvt[cp * 128 + c], xv);
    }
    float bb = bv[c];
    o.x += bb; o.y += bb; o.z += bb; o.w += bb;

    for (int i = 0; i < 16; ++i) {
        float* ob = out + (size_t)(i * CDIM + c) * HW + px0 + q * 4;
        *(float4*)(ob) = o;
    }
}

extern "C" void kernel_launch(void* const* d_in, const int* in_sizes, int n_in,
                              void* d_out, int out_size, void* d_ws, size_t ws_size,
                              hipStream_t stream) {
    const float* x  = (const float*)d_in[0];
    const float* Wk = (const float*)d_in[3];
    const float* Wv = (const float*)d_in[5];
    const float* bv = (const float*)d_in[6];
    const float* Wa = (const float*)d_in[7];
    float* out = (float*)d_out;

    char* ws = (char*)d_ws;
    float* weffp = (float*)(ws);            // 128*28*4 = 14,336 B
    float* wvt   = (float*)(ws + 16384);    // 64 KB, ends 81920

    k_prep<<<78, 256, 0, stream>>>(Wk, Wa, Wv, weffp, wvt);

    const size_t Z_BYTES  = (size_t)16 * 25 * HW * 4;   // 14.75 MB
    const size_t AK_BYTES = (size_t)16 * HW * 4;        // 590 KB
    const size_t NEED_BIG = 81920 + Z_BYTES + AK_BYTES; // 15.4 MB (proven fits)

    if (ws_size >= NEED_BIG) {
        float* z   = (float*)(ws + 81920);
        float* akb = (float*)(ws + 81920 + Z_BYTES);
        float* xb  = (float*)(ws + 81920);              // overlay: z dead after k_ak
        k_z   <<<dim3(36, 16),  256, 0, stream>>>(x, weffp, z);
        k_ak  <<<dim3(36, 16),  256, 0, stream>>>(z, akb);
        k_xbar<<<1152,          256, 0, stream>>>(x, akb, xb);
        k_mat <<<dim3(576, 2),  256, 0, stream>>>(xb, wvt, bv, out);
    } else {
        float* part = (float*)(ws + 81920);             // 4.72 MB
        float* akb  = (float*)(ws + 81920 + 4718592);   // 590 KB
        float* xb   = (float*)(ws + 81920);             // overlay: part dead
        k_conv   <<<dim3(16, 3, 8), 192, 0, stream>>>(x, weffp, part);
        k_combine<<<dim3(36, 16),   256, 0, stream>>>(part, akb);
        k_xbar   <<<1152,           256, 0, stream>>>(x, akb, xb);
        k_mat    <<<dim3(576, 2),   256, 0, stream>>>(xb, wvt, bv, out);
    }
}

// Round 12
// 71.908 us; speedup vs baseline: 1.2243x; 1.2243x over previous
//
#include <hip/hip_runtime.h>

// ConvAttention collapse:
//   softmax_j(Aq[i]+Ak[j]+ba) == softmax_j(Ak_linear[j])   (i-terms & biases cancel)
//   out[i] = Wv * (sum_j sm[j] * x[j]) + bv                (identical for all i)
// Pipeline: k_prep -> k_z (wave-level c-split, scalar weight loads, LDS reduce)
//           -> k_ak (tap shift-sum) -> k_xbar (in-thread softmax + weighted avg)
//           -> k_mat (128x128 matvec, c-split, 16x broadcast store, XCD-swizzled)

#define HW    9216      // 96*96
#define HDIM  96
#define WDIM  96
#define CDIM  128
#define WP    28        // padded taps per row (16B-aligned rows)

__device__ __forceinline__ void fma4(float4& a, const float4& x, const float4& s) {
    a.x += x.x * s.x; a.y += x.y * s.y; a.z += x.z * s.z; a.w += x.w * s.w;
}
__device__ __forceinline__ void axpy4(float4& o, float w, const float4& v) {
    o.x += w * v.x; o.y += w * v.y; o.z += w * v.z; o.w += w * v.w;
}

// ---------------- K0: prep — weffp padded (blocks 0..13) + Wv^T (14..77) --
// weffp[c'][tap] = sum_c Wk[c][c'] * Wa[(128+c)][tap], rows padded to 28.
__global__ void k_prep(const float* __restrict__ Wk, const float* __restrict__ Wa,
                       const float* __restrict__ Wv,
                       float* __restrict__ weffp, float* __restrict__ wvt) {
    const int b = blockIdx.x;
    if (b < 14) {
        int idx = b * 256 + threadIdx.x;
        if (idx < 128 * WP) {
            int cp = idx / WP, tap = idx % WP;
            float s = 0.f;
            if (tap < 25)
                for (int c = 0; c < 128; ++c)
                    s += Wk[c * 128 + cp] * Wa[(128 + c) * 25 + tap];
            weffp[idx] = s;
        }
    } else {
        int idx = (b - 14) * 256 + threadIdx.x;        // 0..16383
        wvt[(idx & 127) * 128 + (idx >> 7)] = Wv[idx]; // wvt[c'][c] = Wv[c][c']
    }
}

// ---------------- K1: z[j][t][hw] = sum_c weff[c][t] * x[j][c][hw] ---------
// Block = 4 waves x 64 px; wave w owns channels [32w, 32w+32). Weight index
// is wave-uniform (readfirstlane base) -> scalar loads, zero VALU/LDS cost.
// acc[25] scalars/lane; cross-wave reduce via LDS bounce.
__global__ __launch_bounds__(256) void k_z(const float* __restrict__ x,
                                           const float* __restrict__ weffp,
                                           float* __restrict__ z) {
    __shared__ float red[4 * 25 * 64];   // 25.6 KB
    const int tid  = threadIdx.x;
    const int wav  = __builtin_amdgcn_readfirstlane(tid >> 6);
    const int lane = tid & 63;
    const int j    = blockIdx.y;
    const int px0  = blockIdx.x * 64;

    const float* wg = weffp + wav * 32 * WP;                       // uniform
    const float* xb = x + ((size_t)j * CDIM + wav * 32) * HW + px0 + lane;

    float acc[25];
    #pragma unroll
    for (int t = 0; t < 25; ++t) acc[t] = 0.f;

    #pragma unroll 2
    for (int c = 0; c < 32; ++c) {
        float xv = xb[(size_t)c * HW];
        #pragma unroll
        for (int t = 0; t < 25; ++t)
            acc[t] = fmaf(wg[c * WP + t], xv, acc[t]);   // weight from SGPR
    }

    #pragma unroll
    for (int t = 0; t < 25; ++t)
        red[(wav * 25 + t) * 64 + lane] = acc[t];
    __syncthreads();

    float* zb = z + (size_t)j * 25 * HW + px0;
    #pragma unroll
    for (int it = 0; it < 7; ++it) {
        int idx = it * 256 + tid;
        if (idx < 25 * 64) {
            int t = idx >> 6, p = idx & 63;
            float s = red[t * 64 + p] + red[(25 + t) * 64 + p]
                    + red[(50 + t) * 64 + p] + red[(75 + t) * 64 + p];
            zb[(size_t)t * HW + p] = s;
        }
    }
}

// ---------------- K2: ak[j][px] = sum_t z[j][t][px + off(t)] (bounded) -----
__global__ __launch_bounds__(256) void k_ak(const float* __restrict__ z,
                                            float* __restrict__ ak) {
    const int j  = blockIdx.y;
    const int px = blockIdx.x * 256 + threadIdx.x;
    const int h = px / WDIM, w = px % WDIM;
    const float* zb = z + (size_t)j * 25 * HW + px;
    float s = 0.f;
    #pragma unroll
    for (int kh = 0; kh < 5; ++kh) {
        const bool rok = (unsigned)(h + kh - 2) < (unsigned)HDIM;
        #pragma unroll
        for (int kw = 0; kw < 5; ++kw) {
            const bool ok = rok && ((unsigned)(w + kw - 2) < (unsigned)WDIM);
            const int t = kh * 5 + kw;
            s += ok ? zb[t * HW + (kh - 2) * WDIM + (kw - 2)] : 0.f;
        }
    }
    ak[(size_t)j * HW + px] = s;
}

// ---------------- fallback conv path (small-ws; proven round 5) ------------
__global__ __launch_bounds__(192) void k_conv(const float* __restrict__ x,
                                              const float* __restrict__ weffp,
                                              float* __restrict__ part) {
    const int j  = blockIdx.x;
    const int rt = blockIdx.y;
    const int g  = blockIdx.z;
    const int c0 = g * 16;
    __shared__ float tile[36 * 104];
    __shared__ float wsm[16 * WP];
    const int tid = threadIdx.x;
    for (int i = tid; i < 16 * WP; i += 192) wsm[i] = weffp[c0 * WP + i];
    const int cq = tid % 24;
    const int rg = tid / 24;
    const int r0 = rg * 4;
    const int rowbase = rt * 32;

    float4 acc[4];
    acc[0] = acc[1] = acc[2] = acc[3] = make_float4(0.f, 0.f, 0.f, 0.f);

    for (int ch = 0; ch < 16; ++ch) {
        const float* xc = x + (size_t)(j * CDIM + c0 + ch) * HW;
        __syncthreads();
        for (int idx = tid; idx < 36 * 26; idx += 192) {
            int r = idx / 26, q = idx % 26;
            int gr = rowbase - 2 + r;
            int gc = q * 4 - 4;
            float4 v = make_float4(0.f, 0.f, 0.f, 0.f);
            if (gr >= 0 && gr < HDIM && gc >= 0 && gc < WDIM)
                v = *(const float4*)(xc + gr * WDIM + gc);
            *(float4*)(tile + r * 104 + q * 4) = v;
        }
        __syncthreads();
        const float* wc = wsm + ch * WP;
        for (int rr = 0; rr < 8; ++rr) {
            const float* trow = tile + (r0 + rr) * 104 + cq * 4;
            float4 a  = *(const float4*)(trow);
            float4 b  = *(const float4*)(trow + 4);
            float4 c4 = *(const float4*)(trow + 8);
            float win[12] = {a.x, a.y, a.z, a.w, b.x, b.y, b.z, b.w,
                             c4.x, c4.y, c4.z, c4.w};
            #pragma unroll
            for (int orow = 0; orow < 4; ++orow) {
                int kh = rr - orow;
                if (kh < 0 || kh > 4) continue;
                #pragma unroll
                for (int kw = 0; kw < 5; ++kw) {
                    float w = wc[kh * 5 + kw];
                    acc[orow].x += w * win[kw + 2];
                    acc[orow].y += w * win[kw + 3];
                    acc[orow].z += w * win[kw + 4];
                    acc[orow].w += w * win[kw + 5];
                }
            }
        }
    }
    float* pr = part + (size_t)(g * 16 + j) * HW;
    #pragma unroll
    for (int orow = 0; orow < 4; ++orow) {
        int row = rowbase + r0 + orow;
        *(float4*)(pr + row * WDIM + cq * 4) = acc[orow];
    }
}

__global__ void k_combine(const float* __restrict__ part, float* __restrict__ ak) {
    const int j  = blockIdx.y;
    const int px = blockIdx.x * 256 + threadIdx.x;
    float s = 0.f;
    #pragma unroll
    for (int g = 0; g < 8; ++g) s += part[(size_t)(g * 16 + j) * HW + px];
    ak[(size_t)j * HW + px] = s;
}

// ---------------- K3: xbar[cp][px] = sum_j softmax_j(ak)[px] * x[j][cp][px] -
__global__ __launch_bounds__(256) void k_xbar(const float* __restrict__ x,
                                              const float* __restrict__ ak,
                                              float* __restrict__ xbar) {
    const int b  = blockIdx.x;
    const int cp = b / 9;
    const int px = (b % 9) * 1024 + threadIdx.x * 4;

    float4 av[16];
    #pragma unroll
    for (int j = 0; j < 16; ++j)
        av[j] = *(const float4*)(ak + (size_t)j * HW + px);

    float4 m = av[0];
    #pragma unroll
    for (int j = 1; j < 16; ++j) {
        m.x = fmaxf(m.x, av[j].x); m.y = fmaxf(m.y, av[j].y);
        m.z = fmaxf(m.z, av[j].z); m.w = fmaxf(m.w, av[j].w);
    }
    float4 tot = make_float4(0.f, 0.f, 0.f, 0.f);
    #pragma unroll
    for (int j = 0; j < 16; ++j) {
        av[j].x = __expf(av[j].x - m.x); av[j].y = __expf(av[j].y - m.y);
        av[j].z = __expf(av[j].z - m.z); av[j].w = __expf(av[j].w - m.w);
        tot.x += av[j].x; tot.y += av[j].y; tot.z += av[j].z; tot.w += av[j].w;
    }
    float4 inv = make_float4(1.f / tot.x, 1.f / tot.y, 1.f / tot.z, 1.f / tot.w);

    float4 acc = make_float4(0.f, 0.f, 0.f, 0.f);
    #pragma unroll
    for (int j = 0; j < 16; ++j) {
        float4 xv = *(const float4*)(x + (size_t)(j * CDIM + cp) * HW + px);
        fma4(acc, xv, av[j]);
    }
    acc.x *= inv.x; acc.y *= inv.y; acc.z *= inv.z; acc.w *= inv.w;
    *(float4*)(xbar + (size_t)cp * HW + px) = acc;
}

// ---------------- K4: out[i][c][px] = Wv*xbar + bv, 16x broadcast ----------
// grid (576, 2): c-split 2-way for occupancy; XCD-chunk px swizzle.
__global__ __launch_bounds__(256) void k_mat(const float* __restrict__ xbar,
                                             const float* __restrict__ wvt,
                                             const float* __restrict__ bv,
                                             float* __restrict__ out) {
    __shared__ float lx[128 * 16];
    const int b    = blockIdx.x;
    const int half = blockIdx.y;
    const int tile = (b & 7) * 72 + (b >> 3);   // 576 = 8 * 72
    const int px0  = tile * 16;
    const int tid  = threadIdx.x;

    #pragma unroll
    for (int i = 0; i < 2; ++i) {
        int lin = tid + i * 256;                // 0..511
        int cp = lin >> 2, q = lin & 3;
        *(float4*)(lx + cp * 16 + q * 4) =
            *(const float4*)(xbar + (size_t)cp * HW + px0 + q * 4);
    }
    __syncthreads();

    const int q = tid & 3;                      // px quad
    const int c = half * 64 + (tid >> 2);       // output channel
    float4 o = make_float4(0.f, 0.f, 0.f, 0.f);
    #pragma unroll 4
    for (int cp = 0; cp < 128; ++cp) {
        float4 xv = *(const float4*)(lx + cp * 16 + q * 4);
        axpy4(o, wvt[cp * 128 + c], xv);
    }
    float bb = bv[c];
    o.x += bb; o.y += bb; o.z += bb; o.w += bb;

    for (int i = 0; i < 16; ++i) {
        float* ob = out + (size_t)(i * CDIM + c) * HW + px0 + q * 4;
        *(float4*)(ob) = o;
    }
}

extern "C" void kernel_launch(void* const* d_in, const int* in_sizes, int n_in,
                              void* d_out, int out_size, void* d_ws, size_t ws_size,
                              hipStream_t stream) {
    const float* x  = (const float*)d_in[0];
    const float* Wk = (const float*)d_in[3];
    const float* Wv = (const float*)d_in[5];
    const float* bv = (const float*)d_in[6];
    const float* Wa = (const float*)d_in[7];
    float* out = (float*)d_out;

    char* ws = (char*)d_ws;
    float* weffp = (float*)(ws);            // 128*28*4 = 14,336 B
    float* wvt   = (float*)(ws + 16384);    // 64 KB, ends 81920

    k_prep<<<78, 256, 0, stream>>>(Wk, Wa, Wv, weffp, wvt);

    const size_t Z_BYTES  = (size_t)16 * 25 * HW * 4;   // 14.75 MB
    const size_t AK_BYTES = (size_t)16 * HW * 4;        // 590 KB
    const size_t NEED_BIG = 81920 + Z_BYTES + AK_BYTES; // 15.4 MB (proven fits)

    if (ws_size >= NEED_BIG) {
        float* z   = (float*)(ws + 81920);
        float* akb = (float*)(ws + 81920 + Z_BYTES);
        float* xb  = (float*)(ws + 81920);              // overlay: z dead after k_ak
        k_z   <<<dim3(144, 16), 256, 0, stream>>>(x, weffp, z);
        k_ak  <<<dim3(36, 16),  256, 0, stream>>>(z, akb);
        k_xbar<<<1152,          256, 0, stream>>>(x, akb, xb);
        k_mat <<<dim3(576, 2),  256, 0, stream>>>(xb, wvt, bv, out);
    } else {
        float* part = (float*)(ws + 81920);             // 4.72 MB
        float* akb  = (float*)(ws + 81920 + 4718592);   // 590 KB
        float* xb   = (float*)(ws + 81920);             // overlay: part dead
        k_conv   <<<dim3(16, 3, 8), 192, 0, stream>>>(x, weffp, part);
        k_combine<<<dim3(36, 16),   256, 0, stream>>>(part, akb);
        k_xbar   <<<1152,           256, 0, stream>>>(x, akb, xb);
        k_mat    <<<dim3(576, 2),   256, 0, stream>>>(xb, wvt, bv, out);
    }
}